// Round 1
// baseline (70.408 us; speedup 1.0000x reference)
//
#include <hip/hip_runtime.h>
#include <math.h>

#define A_N 2048
#define L_N 512
#define D 128
#define B_N 64
#define H1_N 512
#define H2_N 256
#define NCHUNK 8
#define CL 64     // L-chunk per k2 block
#define TA 32     // atom tile

__device__ __forceinline__ int lb_dev(const int* __restrict__ arr, int n, int val) {
    int lo = 0, hi = n;
    while (lo < hi) { int mid = (lo + hi) >> 1; if (arr[mid] < val) lo = mid + 1; else hi = mid; }
    return lo;
}

__device__ __forceinline__ float blk_sum(float v, float* red, int tid) {
    #pragma unroll
    for (int off = 32; off >= 1; off >>= 1) v += __shfl_xor(v, off);
    __syncthreads();
    if ((tid & 63) == 0) red[tid >> 6] = v;
    __syncthreads();
    return red[0] + red[1] + red[2] + red[3];
}

__device__ __forceinline__ float blk_max(float v, float* red, int tid) {
    #pragma unroll
    for (int off = 32; off >= 1; off >>= 1) v = fmaxf(v, __shfl_xor(v, off));
    __syncthreads();
    if ((tid & 63) == 0) red[tid >> 6] = v;
    __syncthreads();
    return fmaxf(fmaxf(red[0], red[1]), fmaxf(red[2], red[3]));
}

// ---------- K1: X = atom_embed @ W_att  [A,128]x[128,128] ----------
__global__ __launch_bounds__(256) void k1_xmul(const float* __restrict__ atom_embed,
                                               const float* __restrict__ W_att,
                                               float* __restrict__ X) {
    __shared__ float ae[8][128];
    const int tid = threadIdx.x;
    const int a0 = blockIdx.x * 8;
    float4 v = reinterpret_cast<const float4*>(atom_embed + (size_t)a0 * D)[tid];
    const int fi = tid * 4;
    ae[fi >> 7][(fi & 127) | 0] = v.x;
    ae[fi >> 7][(fi & 127) | 1] = v.y;
    ae[fi >> 7][(fi & 127) | 2] = v.z;
    ae[fi >> 7][(fi & 127) | 3] = v.w;
    __syncthreads();
    const int d = tid & 127;
    const int ai = tid >> 7;              // 0 or 1
    float acc0 = 0.f, acc1 = 0.f, acc2 = 0.f, acc3 = 0.f;
    for (int k = 0; k < D; ++k) {
        const float w = W_att[k * D + d];
        acc0 += ae[ai + 0][k] * w;
        acc1 += ae[ai + 2][k] * w;
        acc2 += ae[ai + 4][k] * w;
        acc3 += ae[ai + 6][k] * w;
    }
    X[(size_t)(a0 + ai + 0) * D + d] = acc0;
    X[(size_t)(a0 + ai + 2) * D + d] = acc1;
    X[(size_t)(a0 + ai + 4) * D + d] = acc2;
    X[(size_t)(a0 + ai + 6) * D + d] = acc3;
}

// ---------- K2: S chunk + rowmax partials + colmax (Wp) ----------
__global__ __launch_bounds__(256) void k2_scores(const float* __restrict__ X,
                                                 const float* __restrict__ prot,
                                                 const int* __restrict__ splits,
                                                 float* __restrict__ rowmaxp,
                                                 float* __restrict__ Wp) {
    __shared__ float Ps[CL][129];          // prot chunk, padded stride
    __shared__ float Xs[TA][129];          // X tile
    __shared__ float cred[16][CL + 1];     // colmax partials across ti
    const int tid = threadIdx.x;
    const int b = blockIdx.x & (B_N - 1);
    const int chunk = blockIdx.x >> 6;     // 0..7
    const int l0 = chunk * CL;
    const int s = lb_dev(splits, A_N, b);
    const int e = lb_dev(splits, A_N, b + 1);
    const int n = e - s;

    // stage prot chunk [64][128]
    {
        const float4* src = reinterpret_cast<const float4*>(prot + ((size_t)b * L_N + l0) * D);
        for (int i = tid; i < CL * (D / 4); i += 256) {   // 2048 float4
            float4 v = src[i];
            const int l = i >> 5;
            const int k = (i & 31) * 4;
            Ps[l][k] = v.x; Ps[l][k + 1] = v.y; Ps[l][k + 2] = v.z; Ps[l][k + 3] = v.w;
        }
    }

    const int ti = tid >> 4;   // 0..15 -> atoms ti*2, ti*2+1
    const int tj = tid & 15;   // l = li*16 + tj

    float cmax[4] = {-INFINITY, -INFINITY, -INFINITY, -INFINITY};

    const int natile = (n + TA - 1) / TA;
    for (int at = 0; at < natile; ++at) {
        __syncthreads();  // Ps ready (first iter) / previous compute done
        {
            const float4* xsrc = reinterpret_cast<const float4*>(X + (size_t)s * D);
            for (int i = tid; i < TA * (D / 4); i += 256) {  // 1024 float4
                const int j = i >> 5;
                const int k = (i & 31) * 4;
                const int aidx = at * TA + j;
                float4 v;
                if (aidx < n) v = xsrc[(size_t)aidx * (D / 4) + (i & 31)];
                else { v.x = 0.f; v.y = 0.f; v.z = 0.f; v.w = 0.f; }
                Xs[j][k] = v.x; Xs[j][k + 1] = v.y; Xs[j][k + 2] = v.z; Xs[j][k + 3] = v.w;
            }
        }
        __syncthreads();

        float acc[2][4];
        #pragma unroll
        for (int r = 0; r < 2; ++r)
            #pragma unroll
            for (int c = 0; c < 4; ++c) acc[r][c] = 0.f;

        #pragma unroll 4
        for (int k = 0; k < D; ++k) {
            const float x0 = Xs[ti * 2 + 0][k];
            const float x1 = Xs[ti * 2 + 1][k];
            #pragma unroll
            for (int li = 0; li < 4; ++li) {
                const float p = Ps[li * 16 + tj][k];
                acc[0][li] += x0 * p;
                acc[1][li] += x1 * p;
            }
        }

        const int a0i = at * TA + ti * 2;
        const bool v0 = a0i < n, v1 = (a0i + 1) < n;
        float rm0 = -INFINITY, rm1 = -INFINITY;
        #pragma unroll
        for (int li = 0; li < 4; ++li) {
            rm0 = fmaxf(rm0, acc[0][li]);
            rm1 = fmaxf(rm1, acc[1][li]);
            if (v0) cmax[li] = fmaxf(cmax[li], acc[0][li]);
            if (v1) cmax[li] = fmaxf(cmax[li], acc[1][li]);
        }
        #pragma unroll
        for (int off = 8; off >= 1; off >>= 1) {
            rm0 = fmaxf(rm0, __shfl_xor(rm0, off, 16));
            rm1 = fmaxf(rm1, __shfl_xor(rm1, off, 16));
        }
        if (tj == 0) {
            if (v0) rowmaxp[(size_t)(s + a0i) * NCHUNK + chunk] = rm0;
            if (v1) rowmaxp[(size_t)(s + a0i + 1) * NCHUNK + chunk] = rm1;
        }
    }

    #pragma unroll
    for (int li = 0; li < 4; ++li) cred[ti][li * 16 + tj] = cmax[li];
    __syncthreads();
    if (tid < CL) {
        float m = -INFINITY;
        #pragma unroll
        for (int t = 0; t < 16; ++t) m = fmaxf(m, cred[t][tid]);
        Wp[(size_t)b * L_N + l0 + tid] = m;
    }
}

// ---------- K3: per-molecule pools -> HcT [256][64] ----------
__global__ __launch_bounds__(256) void k3_pool(const float* __restrict__ atom_embed,
                                               const float* __restrict__ prot,
                                               const int* __restrict__ splits,
                                               const float* __restrict__ rowmaxp,
                                               const float* __restrict__ Wp,
                                               float* __restrict__ HcT) {
    __shared__ float red[4];
    __shared__ float coef[512];
    __shared__ float ap_s[L_N];
    __shared__ float poolred[128];
    const int tid = threadIdx.x;
    const int b = blockIdx.x;
    const int s = lb_dev(splits, A_N, b);
    const int e = lb_dev(splits, A_N, b + 1);
    const int n = e - s;

    // Sc = sum_a exp(max over chunks)
    float local = 0.f;
    for (int j = tid; j < n; j += 256) {
        const float* rp = rowmaxp + (size_t)(s + j) * NCHUNK;
        float m = rp[0];
        #pragma unroll
        for (int c = 1; c < NCHUNK; ++c) m = fmaxf(m, rp[c]);
        local += expf(m);
    }
    const float Sc = blk_sum(local, red, tid);

    const int d = tid & 127;
    const int h = tid >> 7;

    // atom pool
    float pool = 0.f;
    for (int t0 = 0; t0 < n; t0 += 512) {
        const int cnt = min(512, n - t0);
        __syncthreads();
        for (int j = tid; j < cnt; j += 256) {
            const float* rp = rowmaxp + (size_t)(s + t0 + j) * NCHUNK;
            float m = rp[0];
            #pragma unroll
            for (int c = 1; c < NCHUNK; ++c) m = fmaxf(m, rp[c]);
            coef[j] = expf(m) / Sc;
        }
        __syncthreads();
        for (int j = h; j < cnt; j += 2)
            pool += coef[j] * atom_embed[(size_t)(s + t0 + j) * D + d];
    }
    __syncthreads();
    if (h == 1) poolred[d] = pool;
    __syncthreads();
    if (h == 0) HcT[(size_t)d * B_N + b] = pool + poolred[d];

    // protein softmax over Wp row
    float lm = -INFINITY;
    for (int l = tid; l < L_N; l += 256) lm = fmaxf(lm, Wp[(size_t)b * L_N + l]);
    const float M = blk_max(lm, red, tid);
    float lsum = 0.f;
    for (int l = tid; l < L_N; l += 256) {
        const float ev = expf(Wp[(size_t)b * L_N + l] - M);
        ap_s[l] = ev;
        lsum += ev;
    }
    const float Z = blk_sum(lsum, red, tid);  // also orders ap_s visibility

    float pp = 0.f;
    const float* pbase = prot + ((size_t)b * L_N + h * 256) * D + d;
    for (int l = 0; l < 256; ++l)
        pp += ap_s[h * 256 + l] * pbase[(size_t)l * D];
    __syncthreads();
    if (h == 1) poolred[d] = pp;
    __syncthreads();
    if (h == 0) HcT[(size_t)(D + d) * B_N + b] = (pp + poolred[d]) / Z;
}

// ---------- K4: H1T = relu(Hc @ W1 + b1)^T ----------
__global__ __launch_bounds__(256) void k4_h1(const float* __restrict__ HcT,
                                             const float* __restrict__ W1,
                                             const float* __restrict__ b1,
                                             float* __restrict__ H1T) {
    const int tid = threadIdx.x;
    const int m = tid & 63;
    const int j = blockIdx.x * 4 + (tid >> 6);
    float acc = b1[j];
    for (int k = 0; k < 2 * D; ++k)
        acc += HcT[(size_t)k * B_N + m] * W1[(size_t)k * H1_N + j];
    H1T[(size_t)j * B_N + m] = fmaxf(acc, 0.f);
}

// ---------- K5: H2 cols + partial output dot ----------
__global__ __launch_bounds__(256) void k5_h2(const float* __restrict__ H1T,
                                             const float* __restrict__ W2,
                                             const float* __restrict__ b2,
                                             const float* __restrict__ Wo,
                                             float* __restrict__ outpart) {
    __shared__ float pr[4][64];
    const int tid = threadIdx.x;
    const int m = tid & 63;
    const int jg = tid >> 6;
    const int j = blockIdx.x * 4 + jg;
    float acc = b2[j];
    for (int k = 0; k < H1_N; ++k)
        acc += H1T[(size_t)k * B_N + m] * W2[(size_t)k * H2_N + j];
    const float h2 = fmaxf(acc, 0.f);
    pr[jg][m] = h2 * Wo[j];
    __syncthreads();
    if (tid < 64)
        outpart[(size_t)blockIdx.x * B_N + tid] = pr[0][tid] + pr[1][tid] + pr[2][tid] + pr[3][tid];
}

// ---------- K6: final reduce ----------
__global__ __launch_bounds__(256) void k6_out(const float* __restrict__ outpart,
                                              const float* __restrict__ bo,
                                              float* __restrict__ out) {
    __shared__ float pr[4][64];
    const int tid = threadIdx.x;
    const int m = tid & 63;
    const int g = tid >> 6;
    float s = 0.f;
    for (int blk = g; blk < 64; blk += 4)
        s += outpart[(size_t)blk * B_N + m];
    pr[g][m] = s;
    __syncthreads();
    if (tid < 64)
        out[tid] = pr[0][tid] + pr[1][tid] + pr[2][tid] + pr[3][tid] + bo[0];
}

extern "C" void kernel_launch(void* const* d_in, const int* in_sizes, int n_in,
                              void* d_out, int out_size, void* d_ws, size_t ws_size,
                              hipStream_t stream) {
    const float* atom_embed = (const float*)d_in[0];
    const float* prot       = (const float*)d_in[1];
    const int*   splits     = (const int*)d_in[2];
    const float* W_att      = (const float*)d_in[3];
    const float* W1         = (const float*)d_in[4];
    const float* b1         = (const float*)d_in[5];
    const float* W2         = (const float*)d_in[6];
    const float* b2         = (const float*)d_in[7];
    const float* Wo         = (const float*)d_in[8];
    const float* bo         = (const float*)d_in[9];
    float* out = (float*)d_out;

    float* ws = (float*)d_ws;
    float* X       = ws;  ws += A_N * D;        // 262144
    float* rowmaxp = ws;  ws += A_N * NCHUNK;   // 16384
    float* Wp      = ws;  ws += B_N * L_N;      // 32768
    float* HcT     = ws;  ws += 2 * D * B_N;    // 16384
    float* H1T     = ws;  ws += H1_N * B_N;     // 32768
    float* outpart = ws;  ws += B_N * B_N;      // 4096

    hipLaunchKernelGGL(k1_xmul,  dim3(A_N / 8),      dim3(256), 0, stream, atom_embed, W_att, X);
    hipLaunchKernelGGL(k2_scores,dim3(B_N * NCHUNK), dim3(256), 0, stream, X, prot, splits, rowmaxp, Wp);
    hipLaunchKernelGGL(k3_pool,  dim3(B_N),          dim3(256), 0, stream, atom_embed, prot, splits, rowmaxp, Wp, HcT);
    hipLaunchKernelGGL(k4_h1,    dim3(H1_N / 4),     dim3(256), 0, stream, HcT, W1, b1, H1T);
    hipLaunchKernelGGL(k5_h2,    dim3(H2_N / 4),     dim3(256), 0, stream, H1T, W2, b2, Wo, outpart);
    hipLaunchKernelGGL(k6_out,   dim3(1),            dim3(256), 0, stream, outpart, bo, out);
}

// Round 2
// 61.728 us; speedup vs baseline: 1.1406x; 1.1406x over previous
//
#include <hip/hip_runtime.h>
#include <math.h>

#define A_N 2048
#define L_N 512
#define D 128
#define B_N 64
#define H1_N 512
#define H2_N 256
#define NCHUNK 8
#define CL 64     // L-chunk per k2 block
#define TA 32     // atom tile
#define LDST 132  // padded LDS stride (floats): 16B-aligned rows, 2-way bank alias (free)

__device__ __forceinline__ int lb_dev(const int* __restrict__ arr, int n, int val) {
    int lo = 0, hi = n;
    while (lo < hi) { int mid = (lo + hi) >> 1; if (arr[mid] < val) lo = mid + 1; else hi = mid; }
    return lo;
}

__device__ __forceinline__ float blk_sum(float v, float* red, int tid) {
    #pragma unroll
    for (int off = 32; off >= 1; off >>= 1) v += __shfl_xor(v, off);
    __syncthreads();
    if ((tid & 63) == 0) red[tid >> 6] = v;
    __syncthreads();
    return red[0] + red[1] + red[2] + red[3];
}

__device__ __forceinline__ float blk_max(float v, float* red, int tid) {
    #pragma unroll
    for (int off = 32; off >= 1; off >>= 1) v = fmaxf(v, __shfl_xor(v, off));
    __syncthreads();
    if ((tid & 63) == 0) red[tid >> 6] = v;
    __syncthreads();
    return fmaxf(fmaxf(red[0], red[1]), fmaxf(red[2], red[3]));
}

// ---------- K1: X = atom_embed @ W_att  [A,128]x[128,128] ----------
__global__ __launch_bounds__(256) void k1_xmul(const float* __restrict__ atom_embed,
                                               const float* __restrict__ W_att,
                                               float* __restrict__ X) {
    __shared__ float ae[8][128];
    const int tid = threadIdx.x;
    const int a0 = blockIdx.x * 8;
    float4 v = reinterpret_cast<const float4*>(atom_embed + (size_t)a0 * D)[tid];
    const int fi = tid * 4;
    ae[fi >> 7][(fi & 127) | 0] = v.x;
    ae[fi >> 7][(fi & 127) | 1] = v.y;
    ae[fi >> 7][(fi & 127) | 2] = v.z;
    ae[fi >> 7][(fi & 127) | 3] = v.w;
    __syncthreads();
    const int d = tid & 127;
    const int ai = tid >> 7;              // 0 or 1
    float acc0 = 0.f, acc1 = 0.f, acc2 = 0.f, acc3 = 0.f;
    for (int k = 0; k < D; ++k) {
        const float w = W_att[k * D + d];
        acc0 += ae[ai + 0][k] * w;
        acc1 += ae[ai + 2][k] * w;
        acc2 += ae[ai + 4][k] * w;
        acc3 += ae[ai + 6][k] * w;
    }
    X[(size_t)(a0 + ai + 0) * D + d] = acc0;
    X[(size_t)(a0 + ai + 2) * D + d] = acc1;
    X[(size_t)(a0 + ai + 4) * D + d] = acc2;
    X[(size_t)(a0 + ai + 6) * D + d] = acc3;
}

// ---------- K2: S chunk + rowmax partials + colmax (Wp) ----------
__global__ __launch_bounds__(256) void k2_scores(const float* __restrict__ X,
                                                 const float* __restrict__ prot,
                                                 const int* __restrict__ splits,
                                                 float* __restrict__ rowmaxp,
                                                 float* __restrict__ Wp) {
    __shared__ float Ps[CL][LDST];         // prot chunk
    __shared__ float Xs[TA][LDST];         // X tile
    __shared__ float cred[16][CL + 1];     // colmax partials across ti
    const int tid = threadIdx.x;
    const int b = blockIdx.x & (B_N - 1);
    const int chunk = blockIdx.x >> 6;     // 0..7  (all chunks of b land on XCD b%8)
    const int l0 = chunk * CL;
    const int s = lb_dev(splits, A_N, b);
    const int e = lb_dev(splits, A_N, b + 1);
    const int n = e - s;

    // stage prot chunk [64][128] via float4
    {
        const float4* src = reinterpret_cast<const float4*>(prot + ((size_t)b * L_N + l0) * D);
        for (int i = tid; i < CL * (D / 4); i += 256) {   // 2048 float4
            float4 v = src[i];
            *reinterpret_cast<float4*>(&Ps[i >> 5][(i & 31) * 4]) = v;
        }
    }

    const int ti = tid >> 4;   // 0..15 -> atoms ti*2, ti*2+1
    const int tj = tid & 15;   // l = li*16 + tj

    float cmax[4] = {-INFINITY, -INFINITY, -INFINITY, -INFINITY};

    const int natile = (n + TA - 1) / TA;
    for (int at = 0; at < natile; ++at) {
        __syncthreads();  // Ps ready (first iter) / previous compute done
        {
            const float4* xsrc = reinterpret_cast<const float4*>(X + (size_t)s * D);
            for (int i = tid; i < TA * (D / 4); i += 256) {  // 1024 float4
                const int j = i >> 5;
                const int aidx = at * TA + j;
                float4 v;
                if (aidx < n) v = xsrc[(size_t)aidx * (D / 4) + (i & 31)];
                else { v.x = 0.f; v.y = 0.f; v.z = 0.f; v.w = 0.f; }
                *reinterpret_cast<float4*>(&Xs[j][(i & 31) * 4]) = v;
            }
        }
        __syncthreads();

        float acc[2][4];
        #pragma unroll
        for (int r = 0; r < 2; ++r)
            #pragma unroll
            for (int c = 0; c < 4; ++c) acc[r][c] = 0.f;

        #pragma unroll 2
        for (int k = 0; k < D; k += 4) {
            const float4 x0 = *reinterpret_cast<const float4*>(&Xs[ti * 2 + 0][k]);
            const float4 x1 = *reinterpret_cast<const float4*>(&Xs[ti * 2 + 1][k]);
            #pragma unroll
            for (int li = 0; li < 4; ++li) {
                const float4 p = *reinterpret_cast<const float4*>(&Ps[li * 16 + tj][k]);
                acc[0][li] += x0.x * p.x + x0.y * p.y + x0.z * p.z + x0.w * p.w;
                acc[1][li] += x1.x * p.x + x1.y * p.y + x1.z * p.z + x1.w * p.w;
            }
        }

        const int a0i = at * TA + ti * 2;
        const bool v0 = a0i < n, v1 = (a0i + 1) < n;
        float rm0 = -INFINITY, rm1 = -INFINITY;
        #pragma unroll
        for (int li = 0; li < 4; ++li) {
            rm0 = fmaxf(rm0, acc[0][li]);
            rm1 = fmaxf(rm1, acc[1][li]);
            if (v0) cmax[li] = fmaxf(cmax[li], acc[0][li]);
            if (v1) cmax[li] = fmaxf(cmax[li], acc[1][li]);
        }
        #pragma unroll
        for (int off = 8; off >= 1; off >>= 1) {
            rm0 = fmaxf(rm0, __shfl_xor(rm0, off, 16));
            rm1 = fmaxf(rm1, __shfl_xor(rm1, off, 16));
        }
        if (tj == 0) {
            if (v0) rowmaxp[(size_t)(s + a0i) * NCHUNK + chunk] = rm0;
            if (v1) rowmaxp[(size_t)(s + a0i + 1) * NCHUNK + chunk] = rm1;
        }
    }

    #pragma unroll
    for (int li = 0; li < 4; ++li) cred[ti][li * 16 + tj] = cmax[li];
    __syncthreads();
    if (tid < CL) {
        float m = -INFINITY;
        #pragma unroll
        for (int t = 0; t < 16; ++t) m = fmaxf(m, cred[t][tid]);
        Wp[(size_t)b * L_N + l0 + tid] = m;
    }
}

// ---------- K3: per-molecule pools -> HcT [256][64] ----------
__global__ __launch_bounds__(256) void k3_pool(const float* __restrict__ atom_embed,
                                               const float* __restrict__ prot,
                                               const int* __restrict__ splits,
                                               const float* __restrict__ rowmaxp,
                                               const float* __restrict__ Wp,
                                               float* __restrict__ HcT) {
    __shared__ float red[4];
    __shared__ float coef[512];
    __shared__ float ap_s[L_N];
    __shared__ float4 pred[8][33];
    const int tid = threadIdx.x;
    const int b = blockIdx.x;
    const int s = lb_dev(splits, A_N, b);
    const int e = lb_dev(splits, A_N, b + 1);
    const int n = e - s;

    // Sc = sum_a exp(max over chunks)
    float local = 0.f;
    for (int j = tid; j < n; j += 256) {
        const float* rp = rowmaxp + (size_t)(s + j) * NCHUNK;
        float m = rp[0];
        #pragma unroll
        for (int c = 1; c < NCHUNK; ++c) m = fmaxf(m, rp[c]);
        local += expf(m);
    }
    const float Sc = blk_sum(local, red, tid);

    const int d4 = tid & 31;   // float4 column
    const int g = tid >> 5;    // 0..7 row-group

    // atom pool (float4 lanes, 8-way split over atoms)
    const float4* ae4 = reinterpret_cast<const float4*>(atom_embed);
    float4 pool = {0.f, 0.f, 0.f, 0.f};
    for (int t0 = 0; t0 < n; t0 += 512) {
        const int cnt = min(512, n - t0);
        __syncthreads();
        for (int j = tid; j < cnt; j += 256) {
            const float* rp = rowmaxp + (size_t)(s + t0 + j) * NCHUNK;
            float m = rp[0];
            #pragma unroll
            for (int c = 1; c < NCHUNK; ++c) m = fmaxf(m, rp[c]);
            coef[j] = expf(m) / Sc;
        }
        __syncthreads();
        for (int j = g; j < cnt; j += 8) {
            const float c = coef[j];
            const float4 v = ae4[(size_t)(s + t0 + j) * (D / 4) + d4];
            pool.x += c * v.x; pool.y += c * v.y; pool.z += c * v.z; pool.w += c * v.w;
        }
    }
    __syncthreads();
    pred[g][d4] = pool;
    __syncthreads();
    if (g == 0) {
        float4 acc = pred[0][d4];
        #pragma unroll
        for (int gg = 1; gg < 8; ++gg) {
            const float4 t = pred[gg][d4];
            acc.x += t.x; acc.y += t.y; acc.z += t.z; acc.w += t.w;
        }
        HcT[(size_t)(d4 * 4 + 0) * B_N + b] = acc.x;
        HcT[(size_t)(d4 * 4 + 1) * B_N + b] = acc.y;
        HcT[(size_t)(d4 * 4 + 2) * B_N + b] = acc.z;
        HcT[(size_t)(d4 * 4 + 3) * B_N + b] = acc.w;
    }

    // protein softmax over Wp row
    float lm = -INFINITY;
    for (int l = tid; l < L_N; l += 256) lm = fmaxf(lm, Wp[(size_t)b * L_N + l]);
    const float M = blk_max(lm, red, tid);
    float lsum = 0.f;
    for (int l = tid; l < L_N; l += 256) {
        const float ev = expf(Wp[(size_t)b * L_N + l] - M);
        ap_s[l] = ev;
        lsum += ev;
    }
    const float Z = blk_sum(lsum, red, tid);  // syncs inside -> ap_s visible

    // prot pool (float4 lanes, 8-way split over residues)
    const float4* pr4 = reinterpret_cast<const float4*>(prot) + (size_t)b * L_N * (D / 4);
    float4 pp = {0.f, 0.f, 0.f, 0.f};
    for (int l = g; l < L_N; l += 8) {
        const float w = ap_s[l];
        const float4 v = pr4[(size_t)l * (D / 4) + d4];
        pp.x += w * v.x; pp.y += w * v.y; pp.z += w * v.z; pp.w += w * v.w;
    }
    __syncthreads();
    pred[g][d4] = pp;
    __syncthreads();
    if (g == 0) {
        float4 acc = pred[0][d4];
        #pragma unroll
        for (int gg = 1; gg < 8; ++gg) {
            const float4 t = pred[gg][d4];
            acc.x += t.x; acc.y += t.y; acc.z += t.z; acc.w += t.w;
        }
        const float invZ = 1.f / Z;
        HcT[(size_t)(D + d4 * 4 + 0) * B_N + b] = acc.x * invZ;
        HcT[(size_t)(D + d4 * 4 + 1) * B_N + b] = acc.y * invZ;
        HcT[(size_t)(D + d4 * 4 + 2) * B_N + b] = acc.z * invZ;
        HcT[(size_t)(D + d4 * 4 + 3) * B_N + b] = acc.w * invZ;
    }
}

// ---------- K4: H1T = relu(Hc @ W1 + b1)^T ; also init out = bo ----------
__global__ __launch_bounds__(256) void k4_h1(const float* __restrict__ HcT,
                                             const float* __restrict__ W1,
                                             const float* __restrict__ b1,
                                             const float* __restrict__ bo,
                                             float* __restrict__ H1T,
                                             float* __restrict__ out) {
    const int tid = threadIdx.x;
    if (blockIdx.x == 0 && tid < B_N) out[tid] = bo[0];
    const int m = tid & 63;
    const int j = blockIdx.x * 4 + (tid >> 6);
    float acc0 = b1[j], acc1 = 0.f;
    for (int k = 0; k < 2 * D; k += 2) {
        acc0 += HcT[(size_t)k * B_N + m] * W1[(size_t)k * H1_N + j];
        acc1 += HcT[(size_t)(k + 1) * B_N + m] * W1[(size_t)(k + 1) * H1_N + j];
    }
    H1T[(size_t)j * B_N + m] = fmaxf(acc0 + acc1, 0.f);
}

// ---------- K5: H2 cols + partial output dot -> atomicAdd into out ----------
__global__ __launch_bounds__(256) void k5_h2(const float* __restrict__ H1T,
                                             const float* __restrict__ W2,
                                             const float* __restrict__ b2,
                                             const float* __restrict__ Wo,
                                             float* __restrict__ out) {
    __shared__ float pr[4][64];
    const int tid = threadIdx.x;
    const int m = tid & 63;
    const int jg = tid >> 6;
    const int j = blockIdx.x * 4 + jg;
    float acc0 = b2[j], acc1 = 0.f;
    for (int k = 0; k < H1_N; k += 2) {
        acc0 += H1T[(size_t)k * B_N + m] * W2[(size_t)k * H2_N + j];
        acc1 += H1T[(size_t)(k + 1) * B_N + m] * W2[(size_t)(k + 1) * H2_N + j];
    }
    const float h2 = fmaxf(acc0 + acc1, 0.f);
    pr[jg][m] = h2 * Wo[j];
    __syncthreads();
    if (tid < 64)
        atomicAdd(out + tid, pr[0][tid] + pr[1][tid] + pr[2][tid] + pr[3][tid]);
}

extern "C" void kernel_launch(void* const* d_in, const int* in_sizes, int n_in,
                              void* d_out, int out_size, void* d_ws, size_t ws_size,
                              hipStream_t stream) {
    const float* atom_embed = (const float*)d_in[0];
    const float* prot       = (const float*)d_in[1];
    const int*   splits     = (const int*)d_in[2];
    const float* W_att      = (const float*)d_in[3];
    const float* W1         = (const float*)d_in[4];
    const float* b1         = (const float*)d_in[5];
    const float* W2         = (const float*)d_in[6];
    const float* b2         = (const float*)d_in[7];
    const float* Wo         = (const float*)d_in[8];
    const float* bo         = (const float*)d_in[9];
    float* out = (float*)d_out;

    float* ws = (float*)d_ws;
    float* X       = ws;  ws += A_N * D;        // 262144
    float* rowmaxp = ws;  ws += A_N * NCHUNK;   // 16384
    float* Wp      = ws;  ws += B_N * L_N;      // 32768
    float* HcT     = ws;  ws += 2 * D * B_N;    // 16384
    float* H1T     = ws;  ws += H1_N * B_N;     // 32768

    hipLaunchKernelGGL(k1_xmul,  dim3(A_N / 8),      dim3(256), 0, stream, atom_embed, W_att, X);
    hipLaunchKernelGGL(k2_scores,dim3(B_N * NCHUNK), dim3(256), 0, stream, X, prot, splits, rowmaxp, Wp);
    hipLaunchKernelGGL(k3_pool,  dim3(B_N),          dim3(256), 0, stream, atom_embed, prot, splits, rowmaxp, Wp, HcT);
    hipLaunchKernelGGL(k4_h1,    dim3(H1_N / 4),     dim3(256), 0, stream, HcT, W1, b1, bo, H1T, out);
    hipLaunchKernelGGL(k5_h2,    dim3(H2_N / 4),     dim3(256), 0, stream, H1T, W2, b2, Wo, out);
}